// Round 11
// baseline (716.354 us; speedup 1.0000x reference)
//
#include <hip/hip_runtime.h>

// Sinkhorn, N=4096, D=2, P=1, eps=0.1, 50 iters — persistent cooperative kernel.
// Round-14: quarter geometry — r13's 95% occupancy + r8's work-efficiency.
// r13 post-mortem: occupancy 48->95 and VALUBusy 38->63 but dur flat (611):
// the split geometry ADDED ~60% work/element (lost 2-row amortization, 1M
// redundant recombine-logs, reduce per 32 elems). This round keeps 512 blocks
// x 2 blocks/CU but restores the efficiencies:
//  - block = 32 rows x one col-QUARTER (1024). Wave = 2 rows x full quarter:
//    C-loads amortized over 2 rows; wave_sum IS the quarter-row partial ->
//    no LDS combine, no sPart sync (3 syncs/phase).
//  - coords staged ONCE (persistent LDS, ~21KB total): per-phase stage = 4
//    partial coh_loads + 1 log + 1 LDS store per thread.
//  - partial planes pu[4][4096], pv[4][4096]; consumer recombines
//    u = A - INV_SL*log2(p0+p1+p2+p3) during stage (512K logs/phase, was 1M).
//  - verified leaf/leafdone barrier (RMW lines disjoint from poll lines,
//    32 arrivals/leaf — proven at 512 blocks in r13).
//  - occupancy guard -> verbatim r8 fallback (577us verified) if < 2/CU.

#define NPTS    4096
#define EPS_F   0.1f
#define S_L2E   14.426950408889634f     /* log2(e)/eps */
#define INV_SL  0.0693147180559945f     /* 1/S_L2E = eps*ln2 */
#define A_LOGMU (-0.8317725207f)        /* eps * ln(1/N + 1e-8) */
#define N_ITER  50
#define NLEAF   16
#define BSTRIDE 64                      /* ints between barrier words = 256 B */
/* layout: leaf i at i*BSTRIDE (i<16); [16] unused; leafdone r at (17+r)*BSTRIDE */
#define BAR_INTS ((NLEAF + 1 + NLEAF) * BSTRIDE)

typedef float f4u __attribute__((ext_vector_type(4), aligned(4)));

__device__ __forceinline__ float fexp2(float x) {
#if __has_builtin(__builtin_amdgcn_exp2f)
  return __builtin_amdgcn_exp2f(x);
#else
  float r;
  asm("v_exp_f32 %0, %1" : "=v"(r) : "v"(x));
  return r;
#endif
}

__device__ __forceinline__ float coh_load(const float* p) {
  return __hip_atomic_load(p, __ATOMIC_RELAXED, __HIP_MEMORY_SCOPE_AGENT);
}
__device__ __forceinline__ void coh_store(float* p, float x) {
  __hip_atomic_store(p, x, __ATOMIC_RELAXED, __HIP_MEMORY_SCOPE_AGENT);
}

__device__ __forceinline__ float wave_sum64(float x) {
#pragma unroll
  for (int off = 32; off > 0; off >>= 1) x += __shfl_xor(x, off, 64);
  return x;
}

// Verified barrier (r8/r11/r13): leaf RMW -> winner stores leafdone[leaf]=k ->
// all poll the 16 STORE-ONLY leafdone lines (min >= k, monotone, ABA-free).
// RMW lines and poll lines disjoint (r10: pollers on RMW'd lines serialize).
__device__ __forceinline__ void grid_barrier(int* bar, int k, int arrpl) {
  __syncthreads();
  if (threadIdx.x == 0) {
    const int myleaf = blockIdx.x & (NLEAF - 1);
    const int old = __hip_atomic_fetch_add(bar + myleaf * BSTRIDE, 1,
                                           __ATOMIC_RELAXED,
                                           __HIP_MEMORY_SCOPE_AGENT);
    if (old == arrpl * k - 1)
      __hip_atomic_store(bar + (NLEAF + 1 + myleaf) * BSTRIDE, k,
                         __ATOMIC_RELAXED, __HIP_MEMORY_SCOPE_AGENT);
    for (;;) {
      int mn = k;
#pragma unroll
      for (int rr = 0; rr < NLEAF; ++rr) {
        const int f = __hip_atomic_load(bar + (NLEAF + 1 + rr) * BSTRIDE,
                                        __ATOMIC_RELAXED,
                                        __HIP_MEMORY_SCOPE_AGENT);
        mn = min(mn, f);
      }
      if (mn >= k) break;
      __builtin_amdgcn_s_sleep(1);
    }
  }
  __syncthreads();
}

// ========================= quarter-column kernel ==========================
#define QBLK  512
#define QTPB  1024
#define QARR  (QBLK / NLEAF)            /* 32 arrivals/leaf */
#define QC    1024                      /* cols per block (quarter) */

// Per-phase stage: recombine W for this block's quarter from the 4 partial
// planes (1 col/thread: 4 coh_loads + log + scale + 1 LDS store).
__device__ __forceinline__ void stageWq(const float* __restrict__ part,
                                        float* __restrict__ sW, int tid,
                                        int colbase, bool zero) {
  float w = 0.f;
  if (!zero) {
    const int g = colbase + tid;
    const float s = ((coh_load(part + g) + coh_load(part + NPTS + g)) +
                     coh_load(part + 2 * NPTS + g)) +
                    coh_load(part + 3 * NPTS + g);
    w = (A_LOGMU - INV_SL * __log2f(s)) * S_L2E;
  }
  sW[tid] = w;
  __syncthreads();
}

// One half-iteration: wave owns 2 rows x the block's full quarter.
// wave_sum yields the quarter-row partial directly (no LDS combine).
// Barrier-entry __syncthreads drains lane-0's partial stores before arrival.
__device__ __forceinline__ void phaseq(
    const float rx0, const float ry0, const float rx1, const float ry1,
    const float* __restrict__ sW, const float* __restrict__ sC0,
    const float* __restrict__ sC1, float* __restrict__ pout, int q, int row0,
    int lane) {
  float acc0 = 0.f, acc1 = 0.f;
#pragma unroll
  for (int jt = 0; jt < 4; ++jt) {
    const int j = lane * 4 + jt * 256;
    const float4 W  = *(const float4*)(sW + j);
    const float4 C0 = *(const float4*)(sC0 + j);
    const float4 C1 = *(const float4*)(sC1 + j);
    {
      const float a0 = (W.x - fabsf(rx0 - C0.x)) - fabsf(ry0 - C1.x);
      const float a1 = (W.y - fabsf(rx0 - C0.y)) - fabsf(ry0 - C1.y);
      const float a2 = (W.z - fabsf(rx0 - C0.z)) - fabsf(ry0 - C1.z);
      const float a3 = (W.w - fabsf(rx0 - C0.w)) - fabsf(ry0 - C1.w);
      acc0 += (fexp2(a0) + fexp2(a1)) + (fexp2(a2) + fexp2(a3));
    }
    {
      const float a0 = (W.x - fabsf(rx1 - C0.x)) - fabsf(ry1 - C1.x);
      const float a1 = (W.y - fabsf(rx1 - C0.y)) - fabsf(ry1 - C1.y);
      const float a2 = (W.z - fabsf(rx1 - C0.z)) - fabsf(ry1 - C1.z);
      const float a3 = (W.w - fabsf(rx1 - C0.w)) - fabsf(ry1 - C1.w);
      acc1 += (fexp2(a0) + fexp2(a1)) + (fexp2(a2) + fexp2(a3));
    }
  }
  const float S0 = wave_sum64(acc0);
  const float S1 = wave_sum64(acc1);
  if (lane == 0) {
    coh_store(pout + q * NPTS + row0, S0);
    coh_store(pout + q * NPTS + row0 + 1, S1);
  }
}

__global__ void __launch_bounds__(QTPB, 8)
sinkhorn_quarter(const float* __restrict__ x, const float* __restrict__ y,
                 float* __restrict__ pu, float* __restrict__ pv,
                 float* __restrict__ out, int* __restrict__ bar) {
  __shared__ float sW[QC];
  __shared__ float sC0u[QC], sC1u[QC];   // y-coords (u-phase cols), persistent
  __shared__ float sC0v[QC], sC1v[QC];   // x-coords (v-phase cols), persistent
  __shared__ float sCost[16];

  const int tid  = threadIdx.x;
  const int wv   = tid >> 6;
  const int lane = tid & 63;
  const int q    = blockIdx.x & 3;
  const int rg   = blockIdx.x >> 2;
  const int row0 = rg * 32 + wv * 2;      // this wave's 2 rows
  const int colbase = q * QC;

  float rxu[2], ryu[2], rxv[2], ryv[2];
#pragma unroll
  for (int r = 0; r < 2; ++r) {
    const float2 xr = ((const float2*)x)[row0 + r];
    const float2 yr = ((const float2*)y)[row0 + r];
    rxu[r] = xr.x * S_L2E;  ryu[r] = xr.y * S_L2E;
    rxv[r] = yr.x * S_L2E;  ryv[r] = yr.y * S_L2E;
  }

  {  // persistent coord staging: 1 col/thread, both point sets
    const int g = colbase + tid;
    const float2 yc = ((const float2*)y)[g];
    const float2 xc = ((const float2*)x)[g];
    sC0u[tid] = yc.x * S_L2E;  sC1u[tid] = yc.y * S_L2E;
    sC0v[tid] = xc.x * S_L2E;  sC1v[tid] = xc.y * S_L2E;
  }
  __syncthreads();

  int k = 0;
  for (int it = 0; it < N_ITER; ++it) {
    stageWq(pv, sW, tid, colbase, it == 0);           // W from v partials
    phaseq(rxu[0], ryu[0], rxu[1], ryu[1], sW, sC0u, sC1u, pu, q, row0, lane);
    grid_barrier(bar, ++k, QARR);
    stageWq(pu, sW, tid, colbase, false);             // W from u partials
    phaseq(rxv[0], ryv[0], rxv[1], ryv[1], sW, sC0v, sC1v, pv, q, row0, lane);
    grid_barrier(bar, ++k, QARR);
  }
  stageWq(pv, sW, tid, colbase, false);               // final v

  // ---- output: out[0]=cost, out[1..]=pi, out[1+N*N..]=C ----
  float* __restrict__ pi = out + 1;
  float* __restrict__ cm = out + 1 + (size_t)NPTS * NPTS;
  float uu[2];
#pragma unroll
  for (int r = 0; r < 2; ++r) {
    const int g = row0 + r;
    const float su = ((coh_load(pu + g) + coh_load(pu + NPTS + g)) +
                      coh_load(pu + 2 * NPTS + g)) +
                     coh_load(pu + 3 * NPTS + g);
    uu[r] = (A_LOGMU - INV_SL * __log2f(su)) * S_L2E;
  }

  float costacc = 0.f;
#pragma unroll
  for (int jt = 0; jt < 4; ++jt) {
    const int j = lane * 4 + jt * 256;
    const float4 W  = *(const float4*)(sW + j);
    const float4 C0 = *(const float4*)(sC0u + j);
    const float4 C1 = *(const float4*)(sC1u + j);
#pragma unroll
    for (int r = 0; r < 2; ++r) {
      const float s0 = fabsf(rxu[r] - C0.x) + fabsf(ryu[r] - C1.x);
      const float s1 = fabsf(rxu[r] - C0.y) + fabsf(ryu[r] - C1.y);
      const float s2 = fabsf(rxu[r] - C0.z) + fabsf(ryu[r] - C1.z);
      const float s3 = fabsf(rxu[r] - C0.w) + fabsf(ryu[r] - C1.w);
      const float p0 = fexp2((uu[r] + W.x) - s0);
      const float p1 = fexp2((uu[r] + W.y) - s1);
      const float p2 = fexp2((uu[r] + W.z) - s2);
      const float p3 = fexp2((uu[r] + W.w) - s3);
      costacc = fmaf(p0, s0, costacc);
      costacc = fmaf(p1, s1, costacc);
      costacc = fmaf(p2, s2, costacc);
      costacc = fmaf(p3, s3, costacc);
      const size_t off = (size_t)(row0 + r) * NPTS + colbase + j;
      f4u pvv; pvv.x = p0; pvv.y = p1; pvv.z = p2; pvv.w = p3;
      f4u cv;  cv.x = s0 * INV_SL; cv.y = s1 * INV_SL;
      cv.z = s2 * INV_SL; cv.w = s3 * INV_SL;
      *(f4u*)(pi + off) = pvv;  // out+1 base is 4B-aligned; f4u is aligned(4)
      *(f4u*)(cm + off) = cv;
    }
  }
  const float cw = wave_sum64(costacc);
  if (lane == 0) sCost[wv] = cw;
  __syncthreads();
  if (tid == 0) {
    float c = 0.f;
#pragma unroll
    for (int w = 0; w < 16; ++w) c += sCost[w];
    atomicAdd(out, c * INV_SL);
  }
}

// ===================== fallback: verbatim round-8 kernel ===================
#define FBLK  256
#define FTPB  1024
#define WPB   (FTPB / 64)
#define RPW   2
#define HALFC 2048
#define NJT   (HALFC / 256)
#define FARR  (FBLK / NLEAF)

__device__ __forceinline__ void fb_stageW(const float* __restrict__ win,
                                          float* __restrict__ sW, int tid) {
  const int c = tid * 4;
  const float w0 = coh_load(win + c + 0), w1 = coh_load(win + c + 1);
  const float w2 = coh_load(win + c + 2), w3 = coh_load(win + c + 3);
  float4 W;
  W.x = w0 * S_L2E;  W.y = w1 * S_L2E;  W.z = w2 * S_L2E;  W.w = w3 * S_L2E;
  *(float4*)(sW + c) = W;
  __syncthreads();
}

__device__ __forceinline__ void fb_stageCoords(const float* __restrict__ colp,
                                               float* __restrict__ sC0,
                                               float* __restrict__ sC1,
                                               int tid) {
  const int c = tid * 4;
  const float4 a = ((const float4*)colp)[(c >> 1) + 0];
  const float4 b = ((const float4*)colp)[(c >> 1) + 1];
  float4 C0, C1;
  C0.x = a.x * S_L2E; C0.y = a.z * S_L2E; C0.z = b.x * S_L2E; C0.w = b.z * S_L2E;
  C1.x = a.y * S_L2E; C1.y = a.w * S_L2E; C1.z = b.y * S_L2E; C1.w = b.w * S_L2E;
  *(float4*)(sC0 + c) = C0;
  *(float4*)(sC1 + c) = C1;
}

__device__ __forceinline__ void fb_phase(const float* __restrict__ rx,
                                         const float* __restrict__ ry,
                                         const float* __restrict__ sW,
                                         const float* __restrict__ sC0,
                                         const float* __restrict__ sC1,
                                         float (*sPart)[RPW],
                                         float* __restrict__ wout,
                                         int row0blk, int wv, int lane,
                                         int tid, int base) {
  float acc0 = 0.f, acc1 = 0.f;
#pragma unroll
  for (int jt = 0; jt < NJT; ++jt) {
    const int j = base + jt * 256;
    const float4 W  = *(const float4*)(sW + j);
    const float4 C0 = *(const float4*)(sC0 + j);
    const float4 C1 = *(const float4*)(sC1 + j);
    {
      const float a0 = (W.x - fabsf(rx[0] - C0.x)) - fabsf(ry[0] - C1.x);
      const float a1 = (W.y - fabsf(rx[0] - C0.y)) - fabsf(ry[0] - C1.y);
      const float a2 = (W.z - fabsf(rx[0] - C0.z)) - fabsf(ry[0] - C1.z);
      const float a3 = (W.w - fabsf(rx[0] - C0.w)) - fabsf(ry[0] - C1.w);
      acc0 += (fexp2(a0) + fexp2(a1)) + (fexp2(a2) + fexp2(a3));
    }
    {
      const float a0 = (W.x - fabsf(rx[1] - C0.x)) - fabsf(ry[1] - C1.x);
      const float a1 = (W.y - fabsf(rx[1] - C0.y)) - fabsf(ry[1] - C1.y);
      const float a2 = (W.z - fabsf(rx[1] - C0.z)) - fabsf(ry[1] - C1.z);
      const float a3 = (W.w - fabsf(rx[1] - C0.w)) - fabsf(ry[1] - C1.w);
      acc1 += (fexp2(a0) + fexp2(a1)) + (fexp2(a2) + fexp2(a3));
    }
  }
  const float S0 = wave_sum64(acc0);
  const float S1 = wave_sum64(acc1);
  if (lane == 0) { sPart[wv][0] = S0; sPart[wv][1] = S1; }
  __syncthreads();
  if (tid < 16) {
    const int p = tid >> 1, r = tid & 1;
    const float S = sPart[2 * p][r] + sPart[2 * p + 1][r];
    coh_store(wout + row0blk + p * RPW + r, A_LOGMU - EPS_F * __logf(S));
  }
}

__global__ void __launch_bounds__(FTPB, 4)
sinkhorn_fallback(const float* __restrict__ x, const float* __restrict__ y,
                  float* __restrict__ u, float* __restrict__ v,
                  float* __restrict__ out, int* __restrict__ bar) {
  __shared__ float sW[NPTS];
  __shared__ float sC0y[NPTS], sC1y[NPTS];
  __shared__ float sC0x[NPTS], sC1x[NPTS];
  __shared__ float sPart[WPB][RPW];
  __shared__ float sCost[WPB];

  const int tid  = threadIdx.x;
  const int wv   = tid >> 6;
  const int lane = tid & 63;
  const int row0blk = blockIdx.x * (WPB / 2) * RPW;
  const int row0 = row0blk + (wv >> 1) * RPW;
  const int base = (wv & 1) * HALFC + lane * 4;

  float rxu[RPW], ryu[RPW], rxv[RPW], ryv[RPW];
#pragma unroll
  for (int r = 0; r < RPW; ++r) {
    const float2 xr = ((const float2*)x)[row0 + r];
    const float2 yr = ((const float2*)y)[row0 + r];
    rxu[r] = xr.x * S_L2E;  ryu[r] = xr.y * S_L2E;
    rxv[r] = yr.x * S_L2E;  ryv[r] = yr.y * S_L2E;
  }

  fb_stageCoords(y, sC0y, sC1y, tid);
  fb_stageCoords(x, sC0x, sC1x, tid);
  __syncthreads();

  int k = 0;
  for (int it = 0; it < N_ITER; ++it) {
    fb_stageW(v, sW, tid);
    fb_phase(rxu, ryu, sW, sC0y, sC1y, sPart, u, row0blk, wv, lane, tid, base);
    grid_barrier(bar, ++k, FARR);
    fb_stageW(u, sW, tid);
    fb_phase(rxv, ryv, sW, sC0x, sC1x, sPart, v, row0blk, wv, lane, tid, base);
    grid_barrier(bar, ++k, FARR);
  }
  fb_stageW(v, sW, tid);

  float* __restrict__ pi = out + 1;
  float* __restrict__ cm = out + 1 + (size_t)NPTS * NPTS;
  float uu[RPW];
#pragma unroll
  for (int r = 0; r < RPW; ++r) uu[r] = coh_load(u + row0 + r) * S_L2E;

  float costacc = 0.f;
#pragma unroll 2
  for (int jt = 0; jt < NJT; ++jt) {
    const int j = base + jt * 256;
    const float4 W  = *(const float4*)(sW + j);
    const float4 C0 = *(const float4*)(sC0y + j);
    const float4 C1 = *(const float4*)(sC1y + j);
#pragma unroll
    for (int r = 0; r < RPW; ++r) {
      const float s0 = fabsf(rxu[r] - C0.x) + fabsf(ryu[r] - C1.x);
      const float s1 = fabsf(rxu[r] - C0.y) + fabsf(ryu[r] - C1.y);
      const float s2 = fabsf(rxu[r] - C0.z) + fabsf(ryu[r] - C1.z);
      const float s3 = fabsf(rxu[r] - C0.w) + fabsf(ryu[r] - C1.w);
      const float p0 = fexp2((uu[r] + W.x) - s0);
      const float p1 = fexp2((uu[r] + W.y) - s1);
      const float p2 = fexp2((uu[r] + W.z) - s2);
      const float p3 = fexp2((uu[r] + W.w) - s3);
      costacc = fmaf(p0, s0, costacc);
      costacc = fmaf(p1, s1, costacc);
      costacc = fmaf(p2, s2, costacc);
      costacc = fmaf(p3, s3, costacc);
      const size_t off = (size_t)(row0 + r) * NPTS + j;
      f4u pvv; pvv.x = p0; pvv.y = p1; pvv.z = p2; pvv.w = p3;
      f4u cv;  cv.x = s0 * INV_SL; cv.y = s1 * INV_SL;
      cv.z = s2 * INV_SL; cv.w = s3 * INV_SL;
      *(f4u*)(pi + off) = pvv;
      *(f4u*)(cm + off) = cv;
    }
  }
  const float cw = wave_sum64(costacc);
  if (lane == 0) sCost[wv] = cw;
  __syncthreads();
  if (tid == 0) {
    float c = 0.f;
#pragma unroll
    for (int w = 0; w < WPB; ++w) c += sCost[w];
    atomicAdd(out, c * INV_SL);
  }
}

// ================================ init ====================================
__global__ void sinkhorn_init(float* __restrict__ buf, int* __restrict__ bar,
                              float* __restrict__ out) {
  const int i = blockIdx.x * blockDim.x + threadIdx.x;
  if (i < 8 * NPTS) coh_store(buf + i, 0.f);   // pu[4] + pv[4] planes
  if (i < BAR_INTS)
    __hip_atomic_store(bar + i, 0, __ATOMIC_RELAXED, __HIP_MEMORY_SCOPE_AGENT);
  if (i == 0) out[0] = 0.f;
}

extern "C" void kernel_launch(void* const* d_in, const int* in_sizes, int n_in,
                              void* d_out, int out_size, void* d_ws,
                              size_t ws_size, hipStream_t stream) {
  const float* x = (const float*)d_in[0];
  const float* y = (const float*)d_in[1];
  float* pu = (float*)d_ws;               // [4][4096] u quarter partials
  float* pv = pu + 4 * NPTS;              // [4][4096] v quarter partials
  int* bar = (int*)(pv + 4 * NPTS);
  float* out = (float*)d_out;

  sinkhorn_init<<<dim3(128), dim3(256), 0, stream>>>(pu, bar, out);

  int maxb = 0;                            // host-side query, capture-safe
  hipOccupancyMaxActiveBlocksPerMultiprocessor(&maxb, sinkhorn_quarter, QTPB,
                                               0);

  if (maxb >= 2) {                         // 512 co-resident blocks guaranteed
    void* args[6];
    args[0] = (void*)&x;  args[1] = (void*)&y;
    args[2] = (void*)&pu; args[3] = (void*)&pv;
    args[4] = (void*)&out; args[5] = (void*)&bar;
    hipLaunchCooperativeKernel((void*)sinkhorn_quarter, dim3(QBLK), dim3(QTPB),
                               args, 0, stream);
  } else {                                 // verified round-8 path (577 us)
    float* u = pu;                         // plane 0 as u
    float* v = pv;                         // plane 0 as v (zeroed by init)
    void* args[6];
    args[0] = (void*)&x;  args[1] = (void*)&y;
    args[2] = (void*)&u;  args[3] = (void*)&v;
    args[4] = (void*)&out; args[5] = (void*)&bar;
    hipLaunchCooperativeKernel((void*)sinkhorn_fallback, dim3(FBLK),
                               dim3(FTPB), args, 0, stream);
  }
}

// Round 12
// 708.504 us; speedup vs baseline: 1.0111x; 1.0111x over previous
//
#include <hip/hip_runtime.h>

// Sinkhorn, N=4096, D=2, P=1, eps=0.1, 50 iters — persistent cooperative kernel.
// Round-15: r14 quarter geometry (95% occ, 21KB LDS, verified numerics) with
// the global barrier replaced by per-producer-block FLAGS.
// Why now: r4/5/r12's "protocol failures" were 512-block cooperative-launch
// REJECTIONS (proven by r13/r14: 512 blocks launches at <=25KB LDS) — the
// barrier-free protocol was never actually executed. r8/r13/r14 pin at
// 577-611us across three structures => the shared ~3us/phase barrier chain is
// the floor term. Flags cut it to store-RT + poll-RT and wait only on the
// 128 producers a block actually consumes (skew absorption).
// Protocol rules from this session's measured failures:
//  - 32-bit flags only (r7: 64-bit agent atomics bypass MALL caching).
//  - one writer per flag line (128B stride), pollers read-only (r10: pollers
//    on RMW'd lines serialize at the MALL).
//  - release = __syncthreads (drains partial stores) then flag store; consumer
//    reads partials only after observing the flag (same mechanism as every
//    passing barrier kernel).
//  - planes double-buffered by iteration parity; happens-before chain
//    P.u@it+2 <- v@it+1 flags <- u@it+1 flags <- v@it flags <- R.reads(pu@it)
//    gives 2-iteration write/read separation. Flags monotone, ABA-free.
// Guard: occupancy query; fallback = verbatim r8 kernel (577us verified).

#define NPTS    4096
#define EPS_F   0.1f
#define S_L2E   14.426950408889634f     /* log2(e)/eps */
#define INV_SL  0.0693147180559945f     /* 1/S_L2E = eps*ln2 */
#define A_LOGMU (-0.8317725207f)        /* eps * ln(1/N + 1e-8) */
#define N_ITER  50
#define NLEAF   16
#define BSTRIDE 64
#define BAR_INTS ((NLEAF + 1 + NLEAF) * BSTRIDE)

typedef float f4u __attribute__((ext_vector_type(4), aligned(4)));

__device__ __forceinline__ float fexp2(float x) {
#if __has_builtin(__builtin_amdgcn_exp2f)
  return __builtin_amdgcn_exp2f(x);
#else
  float r;
  asm("v_exp_f32 %0, %1" : "=v"(r) : "v"(x));
  return r;
#endif
}

__device__ __forceinline__ float coh_load(const float* p) {
  return __hip_atomic_load(p, __ATOMIC_RELAXED, __HIP_MEMORY_SCOPE_AGENT);
}
__device__ __forceinline__ void coh_store(float* p, float x) {
  __hip_atomic_store(p, x, __ATOMIC_RELAXED, __HIP_MEMORY_SCOPE_AGENT);
}
__device__ __forceinline__ int coh_load_i(const int* p) {
  return __hip_atomic_load(p, __ATOMIC_RELAXED, __HIP_MEMORY_SCOPE_AGENT);
}
__device__ __forceinline__ void coh_store_i(int* p, int x) {
  __hip_atomic_store(p, x, __ATOMIC_RELAXED, __HIP_MEMORY_SCOPE_AGENT);
}

__device__ __forceinline__ float wave_sum64(float x) {
#pragma unroll
  for (int off = 32; off > 0; off >>= 1) x += __shfl_xor(x, off, 64);
  return x;
}

// ====================== flag-pipelined quarter kernel =====================
#define QBLK  512
#define QTPB  1024
#define QC    1024                      /* cols per block (quarter) */
#define FSTR  32                        /* ints between flags = 128 B */
#define PLANE (4 * NPTS)                /* one parity: 4 quarter planes */

// Stage W for this block's quarter from 4 partial planes (1 col/thread).
__device__ __forceinline__ void stage_from(const float* __restrict__ P,
                                           float* __restrict__ sW, int tid,
                                           int colbase) {
  const int g = colbase + tid;
  const float s = ((coh_load(P + g) + coh_load(P + NPTS + g)) +
                   coh_load(P + 2 * NPTS + g)) +
                  coh_load(P + 3 * NPTS + g);
  sW[tid] = (A_LOGMU - INV_SL * __log2f(s)) * S_L2E;
}

// Wave = 2 rows x full quarter; wave_sum IS the quarter-row partial.
__device__ __forceinline__ void phaseq(
    const float rx0, const float ry0, const float rx1, const float ry1,
    const float* __restrict__ sW, const float* __restrict__ sC0,
    const float* __restrict__ sC1, float* __restrict__ pout, int q, int row0,
    int lane) {
  float acc0 = 0.f, acc1 = 0.f;
#pragma unroll
  for (int jt = 0; jt < 4; ++jt) {
    const int j = lane * 4 + jt * 256;
    const float4 W  = *(const float4*)(sW + j);
    const float4 C0 = *(const float4*)(sC0 + j);
    const float4 C1 = *(const float4*)(sC1 + j);
    {
      const float a0 = (W.x - fabsf(rx0 - C0.x)) - fabsf(ry0 - C1.x);
      const float a1 = (W.y - fabsf(rx0 - C0.y)) - fabsf(ry0 - C1.y);
      const float a2 = (W.z - fabsf(rx0 - C0.z)) - fabsf(ry0 - C1.z);
      const float a3 = (W.w - fabsf(rx0 - C0.w)) - fabsf(ry0 - C1.w);
      acc0 += (fexp2(a0) + fexp2(a1)) + (fexp2(a2) + fexp2(a3));
    }
    {
      const float a0 = (W.x - fabsf(rx1 - C0.x)) - fabsf(ry1 - C1.x);
      const float a1 = (W.y - fabsf(rx1 - C0.y)) - fabsf(ry1 - C1.y);
      const float a2 = (W.z - fabsf(rx1 - C0.z)) - fabsf(ry1 - C1.z);
      const float a3 = (W.w - fabsf(rx1 - C0.w)) - fabsf(ry1 - C1.w);
      acc1 += (fexp2(a0) + fexp2(a1)) + (fexp2(a2) + fexp2(a3));
    }
  }
  const float S0 = wave_sum64(acc0);
  const float S1 = wave_sum64(acc1);
  if (lane == 0) {
    coh_store(pout + q * NPTS + row0, S0);
    coh_store(pout + q * NPTS + row0 + 1, S1);
  }
}

__global__ void __launch_bounds__(QTPB, 8)
sinkhorn_flags(const float* __restrict__ x, const float* __restrict__ y,
               float* __restrict__ pu, float* __restrict__ pv,
               int* __restrict__ uflg, int* __restrict__ vflg,
               float* __restrict__ out) {
  __shared__ float sW[QC];
  __shared__ float sC0u[QC], sC1u[QC];   // y-coords, persistent
  __shared__ float sC0v[QC], sC1v[QC];   // x-coords, persistent
  __shared__ float sCost[16];

  const int tid  = threadIdx.x;
  const int wv   = tid >> 6;
  const int lane = tid & 63;
  const int q    = blockIdx.x & 3;
  const int rg   = blockIdx.x >> 2;
  const int row0 = rg * 32 + wv * 2;
  const int colbase = q * QC;
  const int b = blockIdx.x;
  const int pbase = q * 128;             // this block's 128 producers

  float rxu[2], ryu[2], rxv[2], ryv[2];
#pragma unroll
  for (int r = 0; r < 2; ++r) {
    const float2 xr = ((const float2*)x)[row0 + r];
    const float2 yr = ((const float2*)y)[row0 + r];
    rxu[r] = xr.x * S_L2E;  ryu[r] = xr.y * S_L2E;
    rxv[r] = yr.x * S_L2E;  ryv[r] = yr.y * S_L2E;
  }
  {  // persistent coord staging
    const int g = colbase + tid;
    const float2 yc = ((const float2*)y)[g];
    const float2 xc = ((const float2*)x)[g];
    sC0u[tid] = yc.x * S_L2E;  sC1u[tid] = yc.y * S_L2E;
    sC0v[tid] = xc.x * S_L2E;  sC1v[tid] = xc.y * S_L2E;
  }
  __syncthreads();

  for (int it = 0; it < N_ITER; ++it) {
    // ---------------- u-phase: consume v@(it-1), produce u@it ----------------
    if (it > 0 && tid < 128)
      while (coh_load_i(vflg + (pbase + tid) * FSTR) < it)
        __builtin_amdgcn_s_sleep(1);
    __syncthreads();
    if (it > 0)
      stage_from(pv + ((it - 1) & 1) * PLANE, sW, tid, colbase);
    else
      sW[tid] = 0.f;
    __syncthreads();
    phaseq(rxu[0], ryu[0], rxu[1], ryu[1], sW, sC0u, sC1u,
           pu + (it & 1) * PLANE, q, row0, lane);
    __syncthreads();                     // drains all waves' partial stores
    if (tid == 0) coh_store_i(uflg + b * FSTR, it + 1);

    // ---------------- v-phase: consume u@it, produce v@it --------------------
    if (tid < 128)
      while (coh_load_i(uflg + (pbase + tid) * FSTR) < it + 1)
        __builtin_amdgcn_s_sleep(1);
    __syncthreads();
    stage_from(pu + (it & 1) * PLANE, sW, tid, colbase);
    __syncthreads();
    phaseq(rxv[0], ryv[0], rxv[1], ryv[1], sW, sC0v, sC1v,
           pv + (it & 1) * PLANE, q, row0, lane);
    __syncthreads();
    if (tid == 0) coh_store_i(vflg + b * FSTR, it + 1);
  }

  // ---- epilogue: final v@49 (parity 1) + u@49 for own rows; pi + C + cost ----
  if (tid < 128)
    while (coh_load_i(vflg + (pbase + tid) * FSTR) < N_ITER)
      __builtin_amdgcn_s_sleep(1);
  else if (tid < 132)
    while (coh_load_i(uflg + (rg * 4 + (tid - 128)) * FSTR) < N_ITER)
      __builtin_amdgcn_s_sleep(1);
  __syncthreads();
  stage_from(pv + ((N_ITER - 1) & 1) * PLANE, sW, tid, colbase);
  __syncthreads();

  float* __restrict__ pi = out + 1;
  float* __restrict__ cm = out + 1 + (size_t)NPTS * NPTS;
  const float* __restrict__ PU = pu + ((N_ITER - 1) & 1) * PLANE;
  float uu[2];
#pragma unroll
  for (int r = 0; r < 2; ++r) {
    const int g = row0 + r;
    const float su = ((coh_load(PU + g) + coh_load(PU + NPTS + g)) +
                      coh_load(PU + 2 * NPTS + g)) +
                     coh_load(PU + 3 * NPTS + g);
    uu[r] = (A_LOGMU - INV_SL * __log2f(su)) * S_L2E;
  }

  float costacc = 0.f;
#pragma unroll
  for (int jt = 0; jt < 4; ++jt) {
    const int j = lane * 4 + jt * 256;
    const float4 W  = *(const float4*)(sW + j);
    const float4 C0 = *(const float4*)(sC0u + j);
    const float4 C1 = *(const float4*)(sC1u + j);
#pragma unroll
    for (int r = 0; r < 2; ++r) {
      const float s0 = fabsf(rxu[r] - C0.x) + fabsf(ryu[r] - C1.x);
      const float s1 = fabsf(rxu[r] - C0.y) + fabsf(ryu[r] - C1.y);
      const float s2 = fabsf(rxu[r] - C0.z) + fabsf(ryu[r] - C1.z);
      const float s3 = fabsf(rxu[r] - C0.w) + fabsf(ryu[r] - C1.w);
      const float p0 = fexp2((uu[r] + W.x) - s0);
      const float p1 = fexp2((uu[r] + W.y) - s1);
      const float p2 = fexp2((uu[r] + W.z) - s2);
      const float p3 = fexp2((uu[r] + W.w) - s3);
      costacc = fmaf(p0, s0, costacc);
      costacc = fmaf(p1, s1, costacc);
      costacc = fmaf(p2, s2, costacc);
      costacc = fmaf(p3, s3, costacc);
      const size_t off = (size_t)(row0 + r) * NPTS + colbase + j;
      f4u pvv; pvv.x = p0; pvv.y = p1; pvv.z = p2; pvv.w = p3;
      f4u cv;  cv.x = s0 * INV_SL; cv.y = s1 * INV_SL;
      cv.z = s2 * INV_SL; cv.w = s3 * INV_SL;
      *(f4u*)(pi + off) = pvv;
      *(f4u*)(cm + off) = cv;
    }
  }
  const float cw = wave_sum64(costacc);
  if (lane == 0) sCost[wv] = cw;
  __syncthreads();
  if (tid == 0) {
    float c = 0.f;
#pragma unroll
    for (int w = 0; w < 16; ++w) c += sCost[w];
    atomicAdd(out, c * INV_SL);
  }
}

// ===================== fallback: verbatim round-8 kernel ===================
#define FBLK  256
#define FTPB  1024
#define WPB   (FTPB / 64)
#define RPW   2
#define HALFC 2048
#define NJT   (HALFC / 256)
#define FARR  (FBLK / NLEAF)

__device__ __forceinline__ void grid_barrier(int* bar, int k, int arrpl) {
  __syncthreads();
  if (threadIdx.x == 0) {
    const int myleaf = blockIdx.x & (NLEAF - 1);
    const int old = __hip_atomic_fetch_add(bar + myleaf * BSTRIDE, 1,
                                           __ATOMIC_RELAXED,
                                           __HIP_MEMORY_SCOPE_AGENT);
    if (old == arrpl * k - 1)
      __hip_atomic_store(bar + (NLEAF + 1 + myleaf) * BSTRIDE, k,
                         __ATOMIC_RELAXED, __HIP_MEMORY_SCOPE_AGENT);
    for (;;) {
      int mn = k;
#pragma unroll
      for (int rr = 0; rr < NLEAF; ++rr) {
        const int f = __hip_atomic_load(bar + (NLEAF + 1 + rr) * BSTRIDE,
                                        __ATOMIC_RELAXED,
                                        __HIP_MEMORY_SCOPE_AGENT);
        mn = min(mn, f);
      }
      if (mn >= k) break;
      __builtin_amdgcn_s_sleep(1);
    }
  }
  __syncthreads();
}

__device__ __forceinline__ void fb_stageW(const float* __restrict__ win,
                                          float* __restrict__ sW, int tid) {
  const int c = tid * 4;
  const float w0 = coh_load(win + c + 0), w1 = coh_load(win + c + 1);
  const float w2 = coh_load(win + c + 2), w3 = coh_load(win + c + 3);
  float4 W;
  W.x = w0 * S_L2E;  W.y = w1 * S_L2E;  W.z = w2 * S_L2E;  W.w = w3 * S_L2E;
  *(float4*)(sW + c) = W;
  __syncthreads();
}

__device__ __forceinline__ void fb_stageCoords(const float* __restrict__ colp,
                                               float* __restrict__ sC0,
                                               float* __restrict__ sC1,
                                               int tid) {
  const int c = tid * 4;
  const float4 a = ((const float4*)colp)[(c >> 1) + 0];
  const float4 b = ((const float4*)colp)[(c >> 1) + 1];
  float4 C0, C1;
  C0.x = a.x * S_L2E; C0.y = a.z * S_L2E; C0.z = b.x * S_L2E; C0.w = b.z * S_L2E;
  C1.x = a.y * S_L2E; C1.y = a.w * S_L2E; C1.z = b.y * S_L2E; C1.w = b.w * S_L2E;
  *(float4*)(sC0 + c) = C0;
  *(float4*)(sC1 + c) = C1;
}

__device__ __forceinline__ void fb_phase(const float* __restrict__ rx,
                                         const float* __restrict__ ry,
                                         const float* __restrict__ sW,
                                         const float* __restrict__ sC0,
                                         const float* __restrict__ sC1,
                                         float (*sPart)[RPW],
                                         float* __restrict__ wout,
                                         int row0blk, int wv, int lane,
                                         int tid, int base) {
  float acc0 = 0.f, acc1 = 0.f;
#pragma unroll
  for (int jt = 0; jt < NJT; ++jt) {
    const int j = base + jt * 256;
    const float4 W  = *(const float4*)(sW + j);
    const float4 C0 = *(const float4*)(sC0 + j);
    const float4 C1 = *(const float4*)(sC1 + j);
    {
      const float a0 = (W.x - fabsf(rx[0] - C0.x)) - fabsf(ry[0] - C1.x);
      const float a1 = (W.y - fabsf(rx[0] - C0.y)) - fabsf(ry[0] - C1.y);
      const float a2 = (W.z - fabsf(rx[0] - C0.z)) - fabsf(ry[0] - C1.z);
      const float a3 = (W.w - fabsf(rx[0] - C0.w)) - fabsf(ry[0] - C1.w);
      acc0 += (fexp2(a0) + fexp2(a1)) + (fexp2(a2) + fexp2(a3));
    }
    {
      const float a0 = (W.x - fabsf(rx[1] - C0.x)) - fabsf(ry[1] - C1.x);
      const float a1 = (W.y - fabsf(rx[1] - C0.y)) - fabsf(ry[1] - C1.y);
      const float a2 = (W.z - fabsf(rx[1] - C0.z)) - fabsf(ry[1] - C1.z);
      const float a3 = (W.w - fabsf(rx[1] - C0.w)) - fabsf(ry[1] - C1.w);
      acc1 += (fexp2(a0) + fexp2(a1)) + (fexp2(a2) + fexp2(a3));
    }
  }
  const float S0 = wave_sum64(acc0);
  const float S1 = wave_sum64(acc1);
  if (lane == 0) { sPart[wv][0] = S0; sPart[wv][1] = S1; }
  __syncthreads();
  if (tid < 16) {
    const int p = tid >> 1, r = tid & 1;
    const float S = sPart[2 * p][r] + sPart[2 * p + 1][r];
    coh_store(wout + row0blk + p * RPW + r, A_LOGMU - EPS_F * __logf(S));
  }
}

__global__ void __launch_bounds__(FTPB, 4)
sinkhorn_fallback(const float* __restrict__ x, const float* __restrict__ y,
                  float* __restrict__ u, float* __restrict__ v,
                  float* __restrict__ out, int* __restrict__ bar) {
  __shared__ float sW[NPTS];
  __shared__ float sC0y[NPTS], sC1y[NPTS];
  __shared__ float sC0x[NPTS], sC1x[NPTS];
  __shared__ float sPart[WPB][RPW];
  __shared__ float sCost[WPB];

  const int tid  = threadIdx.x;
  const int wv   = tid >> 6;
  const int lane = tid & 63;
  const int row0blk = blockIdx.x * (WPB / 2) * RPW;
  const int row0 = row0blk + (wv >> 1) * RPW;
  const int base = (wv & 1) * HALFC + lane * 4;

  float rxu[RPW], ryu[RPW], rxv[RPW], ryv[RPW];
#pragma unroll
  for (int r = 0; r < RPW; ++r) {
    const float2 xr = ((const float2*)x)[row0 + r];
    const float2 yr = ((const float2*)y)[row0 + r];
    rxu[r] = xr.x * S_L2E;  ryu[r] = xr.y * S_L2E;
    rxv[r] = yr.x * S_L2E;  ryv[r] = yr.y * S_L2E;
  }

  fb_stageCoords(y, sC0y, sC1y, tid);
  fb_stageCoords(x, sC0x, sC1x, tid);
  __syncthreads();

  int k = 0;
  for (int it = 0; it < N_ITER; ++it) {
    fb_stageW(v, sW, tid);
    fb_phase(rxu, ryu, sW, sC0y, sC1y, sPart, u, row0blk, wv, lane, tid, base);
    grid_barrier(bar, ++k, FARR);
    fb_stageW(u, sW, tid);
    fb_phase(rxv, ryv, sW, sC0x, sC1x, sPart, v, row0blk, wv, lane, tid, base);
    grid_barrier(bar, ++k, FARR);
  }
  fb_stageW(v, sW, tid);

  float* __restrict__ pi = out + 1;
  float* __restrict__ cm = out + 1 + (size_t)NPTS * NPTS;
  float uu[RPW];
#pragma unroll
  for (int r = 0; r < RPW; ++r) uu[r] = coh_load(u + row0 + r) * S_L2E;

  float costacc = 0.f;
#pragma unroll 2
  for (int jt = 0; jt < NJT; ++jt) {
    const int j = base + jt * 256;
    const float4 W  = *(const float4*)(sW + j);
    const float4 C0 = *(const float4*)(sC0y + j);
    const float4 C1 = *(const float4*)(sC1y + j);
#pragma unroll
    for (int r = 0; r < RPW; ++r) {
      const float s0 = fabsf(rxu[r] - C0.x) + fabsf(ryu[r] - C1.x);
      const float s1 = fabsf(rxu[r] - C0.y) + fabsf(ryu[r] - C1.y);
      const float s2 = fabsf(rxu[r] - C0.z) + fabsf(ryu[r] - C1.z);
      const float s3 = fabsf(rxu[r] - C0.w) + fabsf(ryu[r] - C1.w);
      const float p0 = fexp2((uu[r] + W.x) - s0);
      const float p1 = fexp2((uu[r] + W.y) - s1);
      const float p2 = fexp2((uu[r] + W.z) - s2);
      const float p3 = fexp2((uu[r] + W.w) - s3);
      costacc = fmaf(p0, s0, costacc);
      costacc = fmaf(p1, s1, costacc);
      costacc = fmaf(p2, s2, costacc);
      costacc = fmaf(p3, s3, costacc);
      const size_t off = (size_t)(row0 + r) * NPTS + j;
      f4u pvv; pvv.x = p0; pvv.y = p1; pvv.z = p2; pvv.w = p3;
      f4u cv;  cv.x = s0 * INV_SL; cv.y = s1 * INV_SL;
      cv.z = s2 * INV_SL; cv.w = s3 * INV_SL;
      *(f4u*)(pi + off) = pvv;
      *(f4u*)(cm + off) = cv;
    }
  }
  const float cw = wave_sum64(costacc);
  if (lane == 0) sCost[wv] = cw;
  __syncthreads();
  if (tid == 0) {
    float c = 0.f;
#pragma unroll
    for (int w = 0; w < WPB; ++w) c += sCost[w];
    atomicAdd(out, c * INV_SL);
  }
}

// ================================ init ====================================
#define NFLG (QBLK * FSTR)              /* 16384 ints per flag array */

__global__ void sinkhorn_init(float* __restrict__ planes,
                              int* __restrict__ flags,
                              int* __restrict__ bar,
                              float* __restrict__ out) {
  const int i = blockIdx.x * blockDim.x + threadIdx.x;
  if (i < 4 * PLANE) coh_store(planes + i, 0.f);  // pu[2par] + pv[2par]
  if (i < 2 * NFLG)
    __hip_atomic_store(flags + i, 0, __ATOMIC_RELAXED,
                       __HIP_MEMORY_SCOPE_AGENT);
  if (i < BAR_INTS)
    __hip_atomic_store(bar + i, 0, __ATOMIC_RELAXED, __HIP_MEMORY_SCOPE_AGENT);
  if (i == 0) out[0] = 0.f;
}

extern "C" void kernel_launch(void* const* d_in, const int* in_sizes, int n_in,
                              void* d_out, int out_size, void* d_ws,
                              size_t ws_size, hipStream_t stream) {
  const float* x = (const float*)d_in[0];
  const float* y = (const float*)d_in[1];
  float* pu = (float*)d_ws;               // [2][4][4096] floats, 128 KB
  float* pv = pu + 2 * PLANE;             // 128 KB
  int* uflg = (int*)(pv + 2 * PLANE);     // 512 flags * 128 B = 64 KB
  int* vflg = uflg + NFLG;                // 64 KB
  int* bar  = vflg + NFLG;                // fallback barrier
  float* out = (float*)d_out;

  sinkhorn_init<<<dim3(256), dim3(256), 0, stream>>>(pu, uflg, bar, out);

  int maxb = 0;
  hipOccupancyMaxActiveBlocksPerMultiprocessor(&maxb, sinkhorn_flags, QTPB, 0);

  if (maxb >= 2) {                         // 512 co-resident blocks guaranteed
    void* args[7];
    args[0] = (void*)&x;    args[1] = (void*)&y;
    args[2] = (void*)&pu;   args[3] = (void*)&pv;
    args[4] = (void*)&uflg; args[5] = (void*)&vflg;
    args[6] = (void*)&out;
    hipLaunchCooperativeKernel((void*)sinkhorn_flags, dim3(QBLK), dim3(QTPB),
                               args, 0, stream);
  } else {                                 // verified round-8 path (577 us)
    float* u = pu;
    float* v = pu + NPTS;                  // zeroed by init
    void* args[6];
    args[0] = (void*)&x;  args[1] = (void*)&y;
    args[2] = (void*)&u;  args[3] = (void*)&v;
    args[4] = (void*)&out; args[5] = (void*)&bar;
    hipLaunchCooperativeKernel((void*)sinkhorn_fallback, dim3(FBLK),
                               dim3(FTPB), args, 0, stream);
  }
}